// Round 7
// baseline (1301.883 us; speedup 1.0000x reference)
//
#include <hip/hip_runtime.h>

typedef unsigned long long u64;
typedef unsigned int u32;

#define G_ 32
#define L_ 16384
#define D_ 128
#define ONEHOT_ 33554432LL

// ---------------------------------------------------------------------------
// k1: per-window sums -> normalized init codebook c0n [g][w][d]. (R1 verbatim)
// ---------------------------------------------------------------------------
__global__ __launch_bounds__(256) void k1_sums(const float* __restrict__ x,
                                               float* __restrict__ c0n) {
  int blk = blockIdx.x;              // g*64 + w
  const float* xp = x + ((size_t)blk << 15);
  int t = threadIdx.x;
  int d4 = t & 31, r0 = t >> 5;
  float4 acc = make_float4(0.f, 0.f, 0.f, 0.f);
  #pragma unroll 4
  for (int r = r0; r < 256; r += 8) {
    float4 v = *(const float4*)(xp + r * D_ + d4 * 4);
    acc.x += v.x; acc.y += v.y; acc.z += v.z; acc.w += v.w;
  }
  __shared__ float4 part[8][32];
  __shared__ double ssq[33];
  part[r0][d4] = acc;
  __syncthreads();
  if (t < 32) {
    float4 s = part[0][t];
    for (int r = 1; r < 8; ++r) {
      float4 v = part[r][t];
      s.x += v.x; s.y += v.y; s.z += v.z; s.w += v.w;
    }
    part[0][t] = s;
    ssq[t] = (double)s.x * s.x + (double)s.y * s.y + (double)s.z * s.z + (double)s.w * s.w;
  }
  __syncthreads();
  if (t == 0) {
    double tot = 0.0;
    for (int i = 0; i < 32; ++i) tot += ssq[i];
    ssq[32] = 1.0 / sqrt(tot);
  }
  __syncthreads();
  if (t < 32) {
    float rn = (float)ssq[32];
    float4 s = part[0][t];
    float4 c = make_float4(s.x * rn, s.y * rn, s.z * rn, s.w * rn);
    *(float4*)(c0n + ((size_t)blk << 7) + t * 4) = c;
  }
}

// ---------------------------------------------------------------------------
// k2: register-blocked affinity, R6-identical numerics.
// LDS 137 KB -> 1 block/CU -> 2 waves/SIMD; waves_per_eu(2,2) pins the VGPR
// budget at 256 so acc[4][8] (128 VGPR) stays in registers (R6 spilled at the
// compiler's default 4-waves/EU 128-VGPR target: 1.24 GB scratch writes).
// Delta: whole-wave per point, lane covers d=lane,lane+64 -> 2-way banks,
// coalesced 256B re-reads (L2-hot), order-independent i64 fixed point.
// ---------------------------------------------------------------------------
__global__ __launch_bounds__(512)
__attribute__((amdgpu_waves_per_eu(2, 2)))
void k2_assign(const float* __restrict__ x,
               const float* __restrict__ c0n,
               u64* __restrict__ deltaI,
               u64* __restrict__ best) {
  __shared__ float4 cL[64 * 33];      // 33792 B
  __shared__ float4 xq[8][32 * 9];    // 36864 B (per-wave rows of 9 float4)
  __shared__ u64 ldsD[64 * 130];      // 66560 B i64 fixed-point delta
  int g = blockIdx.x >> 3, bsub = blockIdx.x & 7;
  int t = threadIdx.x, lane = t & 63, wv = t >> 6;
  int l15 = lane & 15, pg = lane >> 4;
  const float* xg = x + ((size_t)g << 21);
  const float4* cg4 = (const float4*)(c0n + ((size_t)g << 13));
  for (int i = t; i < 2048; i += 512)
    cL[(i >> 5) * 33 + (i & 31)] = cg4[i];
  for (int i = t; i < 64 * 130; i += 512) ldsD[i] = 0ULL;
  __syncthreads();

  float4* xw = xq[wv];
  int sp = lane >> 1, sh = lane & 1;     // staging: 2 lanes per point
  int sswz = (sp >> 3) << 1;             // stage-write XOR
  int rswz = pg << 1;                    // read XOR (p>>3 == pg)

  float rbv[4]; int rbp[4];
  #pragma unroll
  for (int s = 0; s < 4; ++s) { rbv[s] = -3.0e38f; rbp[s] = 0; }

  int wbase = bsub * 2048 + wv * 256;
  for (int tile = 0; tile < 8; ++tile) {
    int p0 = wbase + tile * 32;
    float4 acc[4][8];
    #pragma unroll
    for (int s = 0; s < 4; ++s)
      #pragma unroll
      for (int j = 0; j < 8; ++j) acc[s][j] = make_float4(0.f, 0.f, 0.f, 0.f);

    for (int q = 0; q < 4; ++q) {
      // per-wave stage: 32 points x 8 float4 (dims q*32..q*32+31)
      const float4* gsrc = (const float4*)(xg + ((size_t)(p0 + sp) << 7) + (q << 5));
      float4* xrow = xw + sp * 9;
      #pragma unroll
      for (int i = 0; i < 4; ++i) {
        int d4l = (sh << 2) + i;
        xrow[d4l ^ sswz] = gsrc[d4l];
      }
      // no barrier: xq[wv] is wave-private; DS pipe is in-order per wave
      #pragma unroll
      for (int d4l = 0; d4l < 8; ++d4l) {
        float4 ca[4];
        #pragma unroll
        for (int s = 0; s < 4; ++s)
          ca[s] = cL[(l15 + (s << 4)) * 33 + (q << 3) + d4l];
        #pragma unroll
        for (int j = 0; j < 8; ++j) {
          float4 xv = xw[(pg * 8 + j) * 9 + (d4l ^ rswz)];
          #pragma unroll
          for (int s = 0; s < 4; ++s) {
            acc[s][j].x += ca[s].x * xv.x;
            acc[s][j].y += ca[s].y * xv.y;
            acc[s][j].z += ca[s].z * xv.z;
            acc[s][j].w += ca[s].w * xv.w;
          }
        }
      }
    }

    int w1s[8];
    #pragma unroll
    for (int j = 0; j < 8; ++j) {
      int p = p0 + pg * 8 + j;
      float av[4];
      #pragma unroll
      for (int s = 0; s < 4; ++s)
        av[s] = (acc[s][j].x + acc[s][j].y) + (acc[s][j].z + acc[s][j].w);
      // per-window running best (strict >, points ascend -> min-p ties)
      #pragma unroll
      for (int s = 0; s < 4; ++s)
        if (av[s] > rbv[s]) { rbv[s] = av[s]; rbp[s] = p; }
      // per-point argmax over 64 windows (min-w ties, numpy semantics)
      float v1 = av[0]; int w1 = l15;
      #pragma unroll
      for (int s = 1; s < 4; ++s)
        if (av[s] > v1) { v1 = av[s]; w1 = l15 + (s << 4); }
      #pragma unroll
      for (int off = 1; off <= 8; off <<= 1) {
        float ov = __shfl_xor(v1, off); int ow = __shfl_xor(w1, off);
        if (ov > v1 || (ov == v1 && ow < w1)) { v1 = ov; w1 = ow; }
      }
      w1s[j] = w1;
    }

    // whole-wave deterministic i64 delta: point i = pg_i*8 + j_i; lane covers
    // d = lane and d = lane+64 (banks lane*2%32: 2-way, free; 256B coalesced)
    #pragma unroll
    for (int i = 0; i < 32; ++i) {
      int w1p = __shfl(w1s[i & 7], (i >> 3) << 4);
      const float* xr = xg + ((size_t)(p0 + i) << 7);
      float va = xr[lane];
      float vb = xr[lane + 64];
      u64* dst = ldsD + w1p * 130 + lane;
      atomicAdd(dst, (u64)(long long)__double2ll_rn((double)va * 4294967296.0));
      atomicAdd(dst + 64, (u64)(long long)__double2ll_rn((double)vb * 4294967296.0));
    }
  }

  // merge per-window best across the 4 pg groups, then global atomicMax
  #pragma unroll
  for (int s = 0; s < 4; ++s) {
    #pragma unroll
    for (int off = 16; off <= 32; off <<= 1) {
      float ov = __shfl_xor(rbv[s], off); int op = __shfl_xor(rbp[s], off);
      if (ov > rbv[s] || (ov == rbv[s] && op < rbp[s])) { rbv[s] = ov; rbp[s] = op; }
    }
  }
  if (pg == 0) {
    #pragma unroll
    for (int s = 0; s < 4; ++s) {
      u32 key = __float_as_uint(rbv[s]);
      key ^= (key & 0x80000000u) ? 0xFFFFFFFFu : 0x80000000u;
      u64 pk = ((u64)key << 32) | (u64)(0xFFFFFFFFu - (u32)rbp[s]);
      atomicMax(&best[(g << 6) + l15 + (s << 4)], pk);
    }
  }

  __syncthreads();
  for (int i = t; i < 8192; i += 512) {
    u64 v = ldsD[(i >> 7) * 130 + (i & 127)];
    if (v) atomicAdd(&deltaI[((size_t)g << 13) + i], v);
  }
}

// ---------------------------------------------------------------------------
// k3: finalize codebook (R1 verbatim); writes cOut (d_out tail) + c2n (ws).
// ---------------------------------------------------------------------------
__global__ __launch_bounds__(128) void k3_final(const float* __restrict__ x,
                                                const float* __restrict__ c0n,
                                                const u64* __restrict__ deltaI,
                                                const u64* __restrict__ best,
                                                float* __restrict__ cOut,
                                                float* __restrict__ c2n) {
  int blk = blockIdx.x, g = blk >> 6;
  int d = threadIdx.x;
  u64 pk = best[blk];
  int bl = (int)(0xFFFFFFFFu - (u32)(pk & 0xFFFFFFFFull));
  float xb = x[((size_t)g << 21) + ((size_t)bl << 7) + d];
  long long di = (long long)deltaI[((size_t)blk << 7) + d];
  double delta = (double)di * (1.0 / 4294967296.0) + (double)xb;

  __shared__ double red[128];
  __shared__ double inv;
  red[d] = delta * delta;
  __syncthreads();
  for (int s = 64; s > 0; s >>= 1) {
    if (d < s) red[d] += red[d + s];
    __syncthreads();
  }
  if (d == 0) inv = 1.0 / sqrt(red[0]);
  __syncthreads();
  float dn = (float)(delta * inv);
  float b2 = 0.5f * c0n[((size_t)blk << 7) + d] + 0.5f * dn;
  __syncthreads();
  red[d] = (double)b2 * b2;
  __syncthreads();
  for (int s = 64; s > 0; s >>= 1) {
    if (d < s) red[d] += red[d + s];
    __syncthreads();
  }
  if (d == 0) inv = 1.0 / sqrt(red[0]);
  __syncthreads();
  float cf = b2 * (float)inv;
  cOut[((size_t)blk << 7) + d] = cf;
  c2n[((size_t)blk << 7) + d] = cf;
}

// ---------------------------------------------------------------------------
// k4: final cos_sim (register-blocked, R6-identical numerics), per-point
// argmax, one-hot row written as float4 by the 16 l15-lanes of each pg group.
// waves_per_eu(2,2): same spill fix as k2.
// ---------------------------------------------------------------------------
__global__ __launch_bounds__(512)
__attribute__((amdgpu_waves_per_eu(2, 2)))
void k4_onehot(const float* __restrict__ x,
               const float* __restrict__ c2n,
               float* __restrict__ out) {
  __shared__ float4 cL[64 * 33];
  __shared__ float4 xq[8][32 * 9];
  int g = blockIdx.x >> 4, bsub = blockIdx.x & 15;
  int t = threadIdx.x, lane = t & 63, wv = t >> 6;
  int l15 = lane & 15, pg = lane >> 4;
  const float* xg = x + ((size_t)g << 21);
  const float4* cg4 = (const float4*)(c2n + ((size_t)g << 13));
  for (int i = t; i < 2048; i += 512)
    cL[(i >> 5) * 33 + (i & 31)] = cg4[i];
  __syncthreads();

  float4* xw = xq[wv];
  int sp = lane >> 1, sh = lane & 1;
  int sswz = (sp >> 3) << 1;
  int rswz = pg << 1;

  int wbase = bsub * 1024 + wv * 128;
  for (int tile = 0; tile < 4; ++tile) {
    int p0 = wbase + tile * 32;
    float4 acc[4][8];
    #pragma unroll
    for (int s = 0; s < 4; ++s)
      #pragma unroll
      for (int j = 0; j < 8; ++j) acc[s][j] = make_float4(0.f, 0.f, 0.f, 0.f);

    for (int q = 0; q < 4; ++q) {
      const float4* gsrc = (const float4*)(xg + ((size_t)(p0 + sp) << 7) + (q << 5));
      float4* xrow = xw + sp * 9;
      #pragma unroll
      for (int i = 0; i < 4; ++i) {
        int d4l = (sh << 2) + i;
        xrow[d4l ^ sswz] = gsrc[d4l];
      }
      #pragma unroll
      for (int d4l = 0; d4l < 8; ++d4l) {
        float4 ca[4];
        #pragma unroll
        for (int s = 0; s < 4; ++s)
          ca[s] = cL[(l15 + (s << 4)) * 33 + (q << 3) + d4l];
        #pragma unroll
        for (int j = 0; j < 8; ++j) {
          float4 xv = xw[(pg * 8 + j) * 9 + (d4l ^ rswz)];
          #pragma unroll
          for (int s = 0; s < 4; ++s) {
            acc[s][j].x += ca[s].x * xv.x;
            acc[s][j].y += ca[s].y * xv.y;
            acc[s][j].z += ca[s].z * xv.z;
            acc[s][j].w += ca[s].w * xv.w;
          }
        }
      }
    }

    #pragma unroll
    for (int j = 0; j < 8; ++j) {
      int p = p0 + pg * 8 + j;
      float av[4];
      #pragma unroll
      for (int s = 0; s < 4; ++s)
        av[s] = (acc[s][j].x + acc[s][j].y) + (acc[s][j].z + acc[s][j].w);
      float v1 = av[0]; int w1 = l15;
      #pragma unroll
      for (int s = 1; s < 4; ++s)
        if (av[s] > v1) { v1 = av[s]; w1 = l15 + (s << 4); }
      #pragma unroll
      for (int off = 1; off <= 8; off <<= 1) {
        float ov = __shfl_xor(v1, off); int ow = __shfl_xor(w1, off);
        if (ov > v1 || (ov == v1 && ow < w1)) { v1 = ov; w1 = ow; }
      }
      // one-hot row p: lane l15 owns cols 4*l15..+3
      int w0 = l15 << 2;
      float4 vv;
      vv.x = (w1 == w0    ) ? 1.f : 0.f;
      vv.y = (w1 == w0 + 1) ? 1.f : 0.f;
      vv.z = (w1 == w0 + 2) ? 1.f : 0.f;
      vv.w = (w1 == w0 + 3) ? 1.f : 0.f;
      *(float4*)(out + (((size_t)(g * L_ + p)) << 6) + w0) = vv;
    }
  }
}

extern "C" void kernel_launch(void* const* d_in, const int* in_sizes, int n_in,
                              void* d_out, int out_size, void* d_ws, size_t ws_size,
                              hipStream_t stream) {
  const float* x = (const float*)d_in[0];
  float* out = (float*)d_out;
  float* cOut = out + ONEHOT_;
  char* ws = (char*)d_ws;
  float* c0n   = (float*)(ws);                     // 1 MiB [g][w][d]
  float* c2n   = (float*)(ws + (1u << 20));        // 1 MiB [g][w][d] final
  u64*  deltaI = (u64*)(ws + (3u << 20));          // 2 MiB [g][w][d] i64 fixed-point
  u64*  best   = (u64*)(ws + (5u << 20));          // 16 KiB [g][w] packed key||~p

  // zero delta accumulators + best (0 == -inf sentinel under the key transform)
  hipMemsetAsync(ws + (3u << 20), 0, (2u << 20) + 16384, stream);

  hipLaunchKernelGGL(k1_sums,   dim3(2048), dim3(256), 0, stream, x, c0n);
  hipLaunchKernelGGL(k2_assign, dim3(256),  dim3(512), 0, stream, x, c0n, deltaI, best);
  hipLaunchKernelGGL(k3_final,  dim3(2048), dim3(128), 0, stream,
                     x, c0n, deltaI, best, cOut, c2n);
  hipLaunchKernelGGL(k4_onehot, dim3(512),  dim3(512), 0, stream, x, c2n, out);
}

// Round 8
// 477.616 us; speedup vs baseline: 2.7258x; 2.7258x over previous
//
#include <hip/hip_runtime.h>

typedef unsigned long long u64;
typedef unsigned int u32;

#define G_ 32
#define L_ 16384
#define D_ 128
#define ONEHOT_ 33554432LL

// ---------------------------------------------------------------------------
// k1: per-window sums -> normalized init codebook c0n [g][w][d]. (R1 verbatim)
// ---------------------------------------------------------------------------
__global__ __launch_bounds__(256) void k1_sums(const float* __restrict__ x,
                                               float* __restrict__ c0n) {
  int blk = blockIdx.x;              // g*64 + w
  const float* xp = x + ((size_t)blk << 15);
  int t = threadIdx.x;
  int d4 = t & 31, r0 = t >> 5;
  float4 acc = make_float4(0.f, 0.f, 0.f, 0.f);
  #pragma unroll 4
  for (int r = r0; r < 256; r += 8) {
    float4 v = *(const float4*)(xp + r * D_ + d4 * 4);
    acc.x += v.x; acc.y += v.y; acc.z += v.z; acc.w += v.w;
  }
  __shared__ float4 part[8][32];
  __shared__ double ssq[33];
  part[r0][d4] = acc;
  __syncthreads();
  if (t < 32) {
    float4 s = part[0][t];
    for (int r = 1; r < 8; ++r) {
      float4 v = part[r][t];
      s.x += v.x; s.y += v.y; s.z += v.z; s.w += v.w;
    }
    part[0][t] = s;
    ssq[t] = (double)s.x * s.x + (double)s.y * s.y + (double)s.z * s.z + (double)s.w * s.w;
  }
  __syncthreads();
  if (t == 0) {
    double tot = 0.0;
    for (int i = 0; i < 32; ++i) tot += ssq[i];
    ssq[32] = 1.0 / sqrt(tot);
  }
  __syncthreads();
  if (t < 32) {
    float rn = (float)ssq[32];
    float4 s = part[0][t];
    float4 c = make_float4(s.x * rn, s.y * rn, s.z * rn, s.w * rn);
    *(float4*)(c0n + ((size_t)blk << 7) + t * 4) = c;
  }
}

// ---------------------------------------------------------------------------
// k2: register-blocked affinity, R6-identical numerics, tile sized for the
// 128-VGPR budget: acc[4][4] float4 = 64 VGPR accumulator (R6/R7's acc[4][8]
// = 128 VGPR spilled -> 2 GB scratch traffic, 18% VALUBusy).
// Lane (l15,pg): windows w = l15+16s, points p = p0 + pg*4 + j. Wave tile =
// 16 points x 64 windows; 16 tiles/wave. Natural 9-float4 row stride gives
// <=2-way LDS banks (free) -> no swizzle.
// Delta: whole-wave per point, lane covers d=lane,lane+64; order-independent
// i64 fixed-point LDS atomics flushed to global (deterministic).
// ---------------------------------------------------------------------------
__global__ __launch_bounds__(512)
void k2_assign(const float* __restrict__ x,
               const float* __restrict__ c0n,
               u64* __restrict__ deltaI,
               u64* __restrict__ best) {
  __shared__ float4 cL[64 * 33];      // 33792 B
  __shared__ float4 xq[8][16 * 9];    // 18432 B (per-wave 16 pts x 8 f4, pad 9)
  __shared__ u64 ldsD[64 * 130];      // 66560 B i64 fixed-point delta
  int g = blockIdx.x >> 3, bsub = blockIdx.x & 7;
  int t = threadIdx.x, lane = t & 63, wv = t >> 6;
  int l15 = lane & 15, pg = lane >> 4;
  const float* xg = x + ((size_t)g << 21);
  const float4* cg4 = (const float4*)(c0n + ((size_t)g << 13));
  for (int i = t; i < 2048; i += 512)
    cL[(i >> 5) * 33 + (i & 31)] = cg4[i];
  for (int i = t; i < 64 * 130; i += 512) ldsD[i] = 0ULL;
  __syncthreads();

  float4* xw = xq[wv];
  int sp = lane >> 2, sh = lane & 3;     // staging: 4 lanes per point

  float rbv[4]; int rbp[4];
  #pragma unroll
  for (int s = 0; s < 4; ++s) { rbv[s] = -3.0e38f; rbp[s] = 0; }

  int wbase = bsub * 2048 + wv * 256;
  for (int tile = 0; tile < 16; ++tile) {
    int p0 = wbase + tile * 16;
    float4 acc[4][4];
    #pragma unroll
    for (int s = 0; s < 4; ++s)
      #pragma unroll
      for (int j = 0; j < 4; ++j) acc[s][j] = make_float4(0.f, 0.f, 0.f, 0.f);

    for (int q = 0; q < 4; ++q) {
      // per-wave stage: 16 points x 8 float4 (dims q*32..q*32+31)
      const float4* gsrc = (const float4*)(xg + ((size_t)(p0 + sp) << 7) + (q << 5));
      float4* xrow = xw + sp * 9;
      xrow[sh * 2]     = gsrc[sh * 2];
      xrow[sh * 2 + 1] = gsrc[sh * 2 + 1];
      // no barrier: xq[wv] is wave-private; DS pipe is in-order per wave
      #pragma unroll
      for (int d4l = 0; d4l < 8; ++d4l) {
        float4 ca[4];
        #pragma unroll
        for (int s = 0; s < 4; ++s)
          ca[s] = cL[(l15 + (s << 4)) * 33 + (q << 3) + d4l];
        #pragma unroll
        for (int j = 0; j < 4; ++j) {
          float4 xv = xw[(pg * 4 + j) * 9 + d4l];
          #pragma unroll
          for (int s = 0; s < 4; ++s) {
            acc[s][j].x += ca[s].x * xv.x;
            acc[s][j].y += ca[s].y * xv.y;
            acc[s][j].z += ca[s].z * xv.z;
            acc[s][j].w += ca[s].w * xv.w;
          }
        }
      }
    }

    int w1s[4];
    #pragma unroll
    for (int j = 0; j < 4; ++j) {
      int p = p0 + pg * 4 + j;
      float av[4];
      #pragma unroll
      for (int s = 0; s < 4; ++s)
        av[s] = (acc[s][j].x + acc[s][j].y) + (acc[s][j].z + acc[s][j].w);
      // per-window running best (strict >, points ascend -> min-p ties)
      #pragma unroll
      for (int s = 0; s < 4; ++s)
        if (av[s] > rbv[s]) { rbv[s] = av[s]; rbp[s] = p; }
      // per-point argmax over 64 windows (min-w ties, numpy semantics)
      float v1 = av[0]; int w1 = l15;
      #pragma unroll
      for (int s = 1; s < 4; ++s)
        if (av[s] > v1) { v1 = av[s]; w1 = l15 + (s << 4); }
      #pragma unroll
      for (int off = 1; off <= 8; off <<= 1) {
        float ov = __shfl_xor(v1, off); int ow = __shfl_xor(w1, off);
        if (ov > v1 || (ov == v1 && ow < w1)) { v1 = ov; w1 = ow; }
      }
      w1s[j] = w1;
    }

    // whole-wave deterministic i64 delta: lane covers d=lane, d=lane+64
    // (u64 banks 2*lane%32: 2-way, free; 256B coalesced L2-hot re-reads)
    #pragma unroll
    for (int i = 0; i < 16; ++i) {
      int w1p = __shfl(w1s[i & 3], (i >> 2) << 4);
      const float* xr = xg + ((size_t)(p0 + i) << 7);
      float va = xr[lane];
      float vb = xr[lane + 64];
      u64* dst = ldsD + w1p * 130 + lane;
      atomicAdd(dst, (u64)(long long)__double2ll_rn((double)va * 4294967296.0));
      atomicAdd(dst + 64, (u64)(long long)__double2ll_rn((double)vb * 4294967296.0));
    }
  }

  // merge per-window best across the 4 pg groups, then global atomicMax
  #pragma unroll
  for (int s = 0; s < 4; ++s) {
    #pragma unroll
    for (int off = 16; off <= 32; off <<= 1) {
      float ov = __shfl_xor(rbv[s], off); int op = __shfl_xor(rbp[s], off);
      if (ov > rbv[s] || (ov == rbv[s] && op < rbp[s])) { rbv[s] = ov; rbp[s] = op; }
    }
  }
  if (pg == 0) {
    #pragma unroll
    for (int s = 0; s < 4; ++s) {
      u32 key = __float_as_uint(rbv[s]);
      key ^= (key & 0x80000000u) ? 0xFFFFFFFFu : 0x80000000u;
      u64 pk = ((u64)key << 32) | (u64)(0xFFFFFFFFu - (u32)rbp[s]);
      atomicMax(&best[(g << 6) + l15 + (s << 4)], pk);
    }
  }

  __syncthreads();
  for (int i = t; i < 8192; i += 512) {
    u64 v = ldsD[(i >> 7) * 130 + (i & 127)];
    if (v) atomicAdd(&deltaI[((size_t)g << 13) + i], v);
  }
}

// ---------------------------------------------------------------------------
// k3: finalize codebook (R1 verbatim); writes cOut (d_out tail) + c2n (ws).
// ---------------------------------------------------------------------------
__global__ __launch_bounds__(128) void k3_final(const float* __restrict__ x,
                                                const float* __restrict__ c0n,
                                                const u64* __restrict__ deltaI,
                                                const u64* __restrict__ best,
                                                float* __restrict__ cOut,
                                                float* __restrict__ c2n) {
  int blk = blockIdx.x, g = blk >> 6;
  int d = threadIdx.x;
  u64 pk = best[blk];
  int bl = (int)(0xFFFFFFFFu - (u32)(pk & 0xFFFFFFFFull));
  float xb = x[((size_t)g << 21) + ((size_t)bl << 7) + d];
  long long di = (long long)deltaI[((size_t)blk << 7) + d];
  double delta = (double)di * (1.0 / 4294967296.0) + (double)xb;

  __shared__ double red[128];
  __shared__ double inv;
  red[d] = delta * delta;
  __syncthreads();
  for (int s = 64; s > 0; s >>= 1) {
    if (d < s) red[d] += red[d + s];
    __syncthreads();
  }
  if (d == 0) inv = 1.0 / sqrt(red[0]);
  __syncthreads();
  float dn = (float)(delta * inv);
  float b2 = 0.5f * c0n[((size_t)blk << 7) + d] + 0.5f * dn;
  __syncthreads();
  red[d] = (double)b2 * b2;
  __syncthreads();
  for (int s = 64; s > 0; s >>= 1) {
    if (d < s) red[d] += red[d + s];
    __syncthreads();
  }
  if (d == 0) inv = 1.0 / sqrt(red[0]);
  __syncthreads();
  float cf = b2 * (float)inv;
  cOut[((size_t)blk << 7) + d] = cf;
  c2n[((size_t)blk << 7) + d] = cf;
}

// ---------------------------------------------------------------------------
// k4: final cos_sim (same acc[4][4] register tile, R6-identical numerics),
// per-point argmax, one-hot row written as float4 by the 16 l15-lanes.
// LDS 52 KB -> 2 blocks/CU -> 4 waves/SIMD.
// ---------------------------------------------------------------------------
__global__ __launch_bounds__(512)
void k4_onehot(const float* __restrict__ x,
               const float* __restrict__ c2n,
               float* __restrict__ out) {
  __shared__ float4 cL[64 * 33];
  __shared__ float4 xq[8][16 * 9];
  int g = blockIdx.x >> 4, bsub = blockIdx.x & 15;
  int t = threadIdx.x, lane = t & 63, wv = t >> 6;
  int l15 = lane & 15, pg = lane >> 4;
  const float* xg = x + ((size_t)g << 21);
  const float4* cg4 = (const float4*)(c2n + ((size_t)g << 13));
  for (int i = t; i < 2048; i += 512)
    cL[(i >> 5) * 33 + (i & 31)] = cg4[i];
  __syncthreads();

  float4* xw = xq[wv];
  int sp = lane >> 2, sh = lane & 3;

  int wbase = bsub * 1024 + wv * 128;
  for (int tile = 0; tile < 8; ++tile) {
    int p0 = wbase + tile * 16;
    float4 acc[4][4];
    #pragma unroll
    for (int s = 0; s < 4; ++s)
      #pragma unroll
      for (int j = 0; j < 4; ++j) acc[s][j] = make_float4(0.f, 0.f, 0.f, 0.f);

    for (int q = 0; q < 4; ++q) {
      const float4* gsrc = (const float4*)(xg + ((size_t)(p0 + sp) << 7) + (q << 5));
      float4* xrow = xw + sp * 9;
      xrow[sh * 2]     = gsrc[sh * 2];
      xrow[sh * 2 + 1] = gsrc[sh * 2 + 1];
      #pragma unroll
      for (int d4l = 0; d4l < 8; ++d4l) {
        float4 ca[4];
        #pragma unroll
        for (int s = 0; s < 4; ++s)
          ca[s] = cL[(l15 + (s << 4)) * 33 + (q << 3) + d4l];
        #pragma unroll
        for (int j = 0; j < 4; ++j) {
          float4 xv = xw[(pg * 4 + j) * 9 + d4l];
          #pragma unroll
          for (int s = 0; s < 4; ++s) {
            acc[s][j].x += ca[s].x * xv.x;
            acc[s][j].y += ca[s].y * xv.y;
            acc[s][j].z += ca[s].z * xv.z;
            acc[s][j].w += ca[s].w * xv.w;
          }
        }
      }
    }

    #pragma unroll
    for (int j = 0; j < 4; ++j) {
      int p = p0 + pg * 4 + j;
      float av[4];
      #pragma unroll
      for (int s = 0; s < 4; ++s)
        av[s] = (acc[s][j].x + acc[s][j].y) + (acc[s][j].z + acc[s][j].w);
      float v1 = av[0]; int w1 = l15;
      #pragma unroll
      for (int s = 1; s < 4; ++s)
        if (av[s] > v1) { v1 = av[s]; w1 = l15 + (s << 4); }
      #pragma unroll
      for (int off = 1; off <= 8; off <<= 1) {
        float ov = __shfl_xor(v1, off); int ow = __shfl_xor(w1, off);
        if (ov > v1 || (ov == v1 && ow < w1)) { v1 = ov; w1 = ow; }
      }
      // one-hot row p: lane l15 owns cols 4*l15..+3 (64 lanes -> 1KB store)
      int w0 = l15 << 2;
      float4 vv;
      vv.x = (w1 == w0    ) ? 1.f : 0.f;
      vv.y = (w1 == w0 + 1) ? 1.f : 0.f;
      vv.z = (w1 == w0 + 2) ? 1.f : 0.f;
      vv.w = (w1 == w0 + 3) ? 1.f : 0.f;
      *(float4*)(out + (((size_t)(g * L_ + p)) << 6) + w0) = vv;
    }
  }
}

extern "C" void kernel_launch(void* const* d_in, const int* in_sizes, int n_in,
                              void* d_out, int out_size, void* d_ws, size_t ws_size,
                              hipStream_t stream) {
  const float* x = (const float*)d_in[0];
  float* out = (float*)d_out;
  float* cOut = out + ONEHOT_;
  char* ws = (char*)d_ws;
  float* c0n   = (float*)(ws);                     // 1 MiB [g][w][d]
  float* c2n   = (float*)(ws + (1u << 20));        // 1 MiB [g][w][d] final
  u64*  deltaI = (u64*)(ws + (3u << 20));          // 2 MiB [g][w][d] i64 fixed-point
  u64*  best   = (u64*)(ws + (5u << 20));          // 16 KiB [g][w] packed key||~p

  // zero delta accumulators + best (0 == -inf sentinel under the key transform)
  hipMemsetAsync(ws + (3u << 20), 0, (2u << 20) + 16384, stream);

  hipLaunchKernelGGL(k1_sums,   dim3(2048), dim3(256), 0, stream, x, c0n);
  hipLaunchKernelGGL(k2_assign, dim3(256),  dim3(512), 0, stream, x, c0n, deltaI, best);
  hipLaunchKernelGGL(k3_final,  dim3(2048), dim3(128), 0, stream,
                     x, c0n, deltaI, best, cOut, c2n);
  hipLaunchKernelGGL(k4_onehot, dim3(512),  dim3(512), 0, stream, x, c2n, out);
}